// Round 4
// baseline (184.693 us; speedup 1.0000x reference)
//
#include <hip/hip_runtime.h>
#include <hip/hip_bf16.h>

#define T 8192
#define D 128
#define NSPLIT 16
#define JLEN (T / NSPLIT)   /* 512 */
#define BN 32
#define NITER (JLEN / BN)   /* 16 */
#define BM 128              /* rows per workgroup */
#define LOG2E 1.44269504088896f

typedef _Float16 half2_t __attribute__((ext_vector_type(2)));
typedef _Float16 half4_t __attribute__((ext_vector_type(4)));
typedef _Float16 half8_t __attribute__((ext_vector_type(8)));
typedef __fp16 fp16x2_t __attribute__((ext_vector_type(2)));
typedef float floatx4 __attribute__((ext_vector_type(4)));
typedef float floatx16 __attribute__((ext_vector_type(16)));

// ---------------------------------------------------------------------------
// prep: q16 = f16(question), qT16 = transpose, cm16 = f16(ctx*w_m*log2e),
// qq2[j] = (question[j].w_q)*log2e.  Also zeroes h (atomic target for tail).
// grid 256 (32 rows/block), block 256
// ---------------------------------------------------------------------------
__global__ void prep_kernel(const float* __restrict__ x, const float* __restrict__ kern,
                            _Float16* __restrict__ q16, _Float16* __restrict__ qT16,
                            _Float16* __restrict__ cm16, float* __restrict__ qq2,
                            float* __restrict__ h) {
    const float* context  = x;
    const float* question = x + (size_t)T * D;
    const float* wq = kern + D;
    const float* wm = kern + 2 * D;
    __shared__ __align__(16) _Float16 tile[32][136];
    int j0 = blockIdx.x * 32;
    int t = threadIdx.x;
    if (blockIdx.x == 0 && t < 128) h[t] = 0.f;   // zero atomic accumulator
    int c4 = t & 31;       // float4 index within row (0..31)
    int rsub = t >> 5;     // 0..7
    float4 wqv = ((const float4*)wq)[c4];
    float4 wmv = ((const float4*)wm)[c4];
    for (int p = 0; p < 4; ++p) {
        int row = p * 8 + rsub;
        float4 q = ((const float4*)(question + (size_t)(j0 + row) * D))[c4];
        float4 c = ((const float4*)(context  + (size_t)(j0 + row) * D))[c4];
        half4_t qh;
        qh[0] = (_Float16)q.x; qh[1] = (_Float16)q.y; qh[2] = (_Float16)q.z; qh[3] = (_Float16)q.w;
        *(half4_t*)(q16 + (size_t)(j0 + row) * D + c4 * 4) = qh;
        *(half4_t*)&tile[row][c4 * 4] = qh;
        half4_t ch;
        ch[0] = (_Float16)(c.x * wmv.x * LOG2E); ch[1] = (_Float16)(c.y * wmv.y * LOG2E);
        ch[2] = (_Float16)(c.z * wmv.z * LOG2E); ch[3] = (_Float16)(c.w * wmv.w * LOG2E);
        *(half4_t*)(cm16 + (size_t)(j0 + row) * D + c4 * 4) = ch;
        float s = q.x * wqv.x + q.y * wqv.y + q.z * wqv.z + q.w * wqv.w;
        for (int dx = 1; dx <= 16; dx <<= 1) s += __shfl_xor(s, dx);
        if (c4 == 0) qq2[j0 + row] = s * LOG2E;
    }
    __syncthreads();
    for (int p = 0; p < 2; ++p) {
        int chunk = t + p * 256;
        int d = chunk >> 2, jo = (chunk & 3) * 8;
        half8_t v;
        for (int s2 = 0; s2 < 8; ++s2) v[s2] = tile[jo + s2][d];
        *(half8_t*)(qT16 + (size_t)d * T + j0 + jo) = v;
    }
}

// ---------------------------------------------------------------------------
// flash, 32x32x16, occupancy-first (R2 structure, half-size tiles):
//  - latency-bound kernel (R2 counters: MFMA 25%, VALU 28%, HBM 4%, nothing
//    saturated at 2 waves/SIMD).  Fix = TLP: LDS 35.8KB + VGPR<=128 ->
//    4 blocks/CU, grid 1024 = exactly 4/CU (4 waves/SIMD, 2x latency hiding).
//  - one wave = 32 queries (query = lane&31 col of the C tile -> m/l/rinv are
//    per-lane scalars).  sigma (bits2<->3 swap) on Kt row reads makes St's
//    C-regs the PV B-fragments verbatim (zero shuffles).
//  - Kt stride 272B (bank-group stride 1, conflict-free); Vt granule rotation
//    mod 4 (64 lanes -> 8 lanes per bank-group = b128 minimum).
//  - LDS double-buffered, ONE barrier/iter; reg staging 2 tiles ahead.
//  - exact defer-max rescale (wave-uniform branch).
// grid 1024 = 64 row-blocks x 16 j-splits, block 256 (4 waves, 32 rows/wave)
// NOTE: NO cross-tile score pipeline (R3: +64 VGPR state -> scratch spills,
// WRITE_SIZE 8.7->38MB, 40% regression).  Spill tripwire: WRITE_SIZE ~8.7MB.
// ---------------------------------------------------------------------------
__global__ __launch_bounds__(256, 4)
void flash_kernel(const _Float16* __restrict__ q16, const _Float16* __restrict__ qT16,
                  const _Float16* __restrict__ cm16, const float* __restrict__ qq2,
                  unsigned char* __restrict__ Opart, float* __restrict__ mpart,
                  float* __restrict__ lpart) {
    __shared__ __align__(16) _Float16 Kt[2][32][136];  // [key][d], stride 272B
    __shared__ __align__(16) _Float16 Vt[2][128][32];  // [d][swizzled key granule]
    __shared__ __align__(16) float qqs[JLEN];          // biases for this split (2KB)

    const int bx = blockIdx.x;
    const int rb = bx >> 4;
    const int sp = bx & 15;
    const int tid = threadIdx.x;
    const int wave = tid >> 6;
    const int lane = tid & 63;
    const int l31 = lane & 31;
    const int h = lane >> 5;
    const int rbase = rb * BM + wave * 32;
    const int q = rbase + l31;                  // this lane's query row
    // sigma: swap bits 2<->3 (involution). Makes St C-regs == PV B-frags.
    const int sig = (l31 & 19) | ((l31 & 4) << 1) | ((l31 & 8) >> 1);

    if (tid < 128) ((float4*)qqs)[tid] = ((const float4*)(qq2 + (size_t)sp * JLEN))[tid];

    // B-operand of St: lane holds cm16[q][ks*16 + h*8 + 0..7]
    half8_t qfrag[8];
#pragma unroll
    for (int ks = 0; ks < 8; ++ks)
        qfrag[ks] = *(const half8_t*)(cm16 + (size_t)q * D + ks * 16 + h * 8);

    floatx16 acc[4];   // acc[nt]: O^T tile, row = d-within-tile, col = query
#pragma unroll
    for (int nt = 0; nt < 4; ++nt)
#pragma unroll
        for (int r = 0; r < 16; ++r) acc[nt][r] = 0.f;
    float m_run = -INFINITY, l_run = 0.f;

    const int j0 = sp * JLEN;
    half8_t kreg[2], vreg[2];
    // tile 0 -> LDS buf0 directly
#pragma unroll
    for (int k = 0; k < 2; ++k) {
        int idx = tid + k * 256;
        kreg[k] = *(const half8_t*)(q16 + (size_t)(j0 + (idx >> 4)) * D + (idx & 15) * 8);
        vreg[k] = *(const half8_t*)(qT16 + (size_t)(idx >> 2) * T + j0 + (idx & 3) * 8);
    }
#pragma unroll
    for (int k = 0; k < 2; ++k) {
        int idx = tid + k * 256;
        *(half8_t*)&Kt[0][idx >> 4][(idx & 15) * 8] = kreg[k];
        int dr = idx >> 2, c4g = idx & 3;
        *(half8_t*)&Vt[0][dr][((c4g + (dr & 3)) & 3) * 8] = vreg[k];
    }
    // prefetch tile 1 -> regs
#pragma unroll
    for (int k = 0; k < 2; ++k) {
        int idx = tid + k * 256;
        kreg[k] = *(const half8_t*)(q16 + (size_t)(j0 + BN + (idx >> 4)) * D + (idx & 15) * 8);
        vreg[k] = *(const half8_t*)(qT16 + (size_t)(idx >> 2) * T + j0 + BN + (idx & 3) * 8);
    }
    __syncthreads();

    for (int it = 0; it < NITER; ++it) {
        const int cur = it & 1;
        // ---- commit tile it+1 into the other buffer ----
        if (it + 1 < NITER) {
#pragma unroll
            for (int k = 0; k < 2; ++k) {
                int idx = tid + k * 256;
                *(half8_t*)&Kt[cur ^ 1][idx >> 4][(idx & 15) * 8] = kreg[k];
                int dr = idx >> 2, c4g = idx & 3;
                *(half8_t*)&Vt[cur ^ 1][dr][((c4g + (dr & 3)) & 3) * 8] = vreg[k];
            }
        }
        // ---- issue tile it+2 global loads (latency overlaps compute) ----
        if (it + 2 < NITER) {
            int jn = j0 + (it + 2) * BN;
#pragma unroll
            for (int k = 0; k < 2; ++k) {
                int idx = tid + k * 256;
                kreg[k] = *(const half8_t*)(q16 + (size_t)(jn + (idx >> 4)) * D + (idx & 15) * 8);
                vreg[k] = *(const half8_t*)(qT16 + (size_t)(idx >> 2) * T + jn + (idx & 3) * 8);
            }
        }

        // ---- St = K Qm^T + bias (C-init); keys via sigma: key(reg) =
        //      (reg&3) + 4*((reg>>2)&1) + 8h + 16*(reg>>3)
        floatx16 St;
        {
            const float* qb = &qqs[it * 32];
            float4 b0 = *(const float4*)(qb + 8 * h);
            float4 b1 = *(const float4*)(qb + 4 + 8 * h);
            float4 b2 = *(const float4*)(qb + 16 + 8 * h);
            float4 b3 = *(const float4*)(qb + 20 + 8 * h);
            St[0]  = b0.x; St[1]  = b0.y; St[2]  = b0.z; St[3]  = b0.w;
            St[4]  = b1.x; St[5]  = b1.y; St[6]  = b1.z; St[7]  = b1.w;
            St[8]  = b2.x; St[9]  = b2.y; St[10] = b2.z; St[11] = b2.w;
            St[12] = b3.x; St[13] = b3.y; St[14] = b3.z; St[15] = b3.w;
            __builtin_amdgcn_s_setprio(1);
#pragma unroll
            for (int ks = 0; ks < 8; ++ks) {
                half8_t a = *(const half8_t*)&Kt[cur][sig][ks * 16 + h * 8];
                St = __builtin_amdgcn_mfma_f32_32x32x16_f16(a, qfrag[ks], St, 0, 0, 0);
            }
            __builtin_amdgcn_s_setprio(0);
        }

        // ---- online softmax (exact defer-max); tree reductions ----
        float t4[4];
#pragma unroll
        for (int r = 0; r < 4; ++r)
            t4[r] = fmaxf(fmaxf(St[r], St[r + 4]), fmaxf(St[r + 8], St[r + 12]));
        float mx = fmaxf(fmaxf(t4[0], t4[1]), fmaxf(t4[2], t4[3]));
        mx = fmaxf(mx, __shfl_xor(mx, 32));
        if (__any(mx > m_run)) {
            float mnew = fmaxf(m_run, mx);
            float alpha = __builtin_amdgcn_exp2f(m_run - mnew);
#pragma unroll
            for (int nt = 0; nt < 4; ++nt)
#pragma unroll
                for (int r = 0; r < 16; ++r) acc[nt][r] *= alpha;
            l_run *= alpha;
            m_run = mnew;
        }
        int pk_[2][4];
        float psa[4] = {0.f, 0.f, 0.f, 0.f};
#pragma unroll
        for (int kb = 0; kb < 2; ++kb)
#pragma unroll
            for (int r = 0; r < 4; ++r) {
                float p0 = __builtin_amdgcn_exp2f(St[kb * 8 + 2 * r]     - m_run);
                float p1 = __builtin_amdgcn_exp2f(St[kb * 8 + 2 * r + 1] - m_run);
                psa[r] += p0 + p1;
                fp16x2_t pk = __builtin_amdgcn_cvt_pkrtz(p0, p1);
                pk_[kb][r] = __builtin_bit_cast(int, pk);
            }
        float ps = (psa[0] + psa[1]) + (psa[2] + psa[3]);
        ps += __shfl_xor(ps, 32);
        l_run += ps;

        // ---- O^T += V^T P from Vt[cur]; B-frag = packed St regs (sigma) ----
        __builtin_amdgcn_s_setprio(1);
#pragma unroll
        for (int kb = 0; kb < 2; ++kb) {
            int4 w;
            w.x = pk_[kb][0]; w.y = pk_[kb][1];
            w.z = pk_[kb][2]; w.w = pk_[kb][3];
            half8_t pb = __builtin_bit_cast(half8_t, w);
            const int pg = ((kb * 2 + h) + (l31 & 3)) & 3;
#pragma unroll
            for (int nt = 0; nt < 4; ++nt) {
                half8_t va = *(const half8_t*)&Vt[cur][nt * 32 + l31][pg * 8];
                acc[nt] = __builtin_amdgcn_mfma_f32_32x32x16_f16(va, pb, acc[nt], 0, 0, 0);
            }
        }
        __builtin_amdgcn_s_setprio(0);
        __syncthreads();
    }

    // ---- finalize: normalized O (O/l) as fp8 e4m3, 4B packed stores; m,l ----
    if (h == 0) {
        mpart[(size_t)sp * T + q] = m_run;
        lpart[(size_t)sp * T + q] = l_run;
    }
    float rinv = 1.0f / l_run;
#pragma unroll
    for (int nt = 0; nt < 4; ++nt)
#pragma unroll
        for (int rg = 0; rg < 4; ++rg) {
            float v0 = acc[nt][rg * 4 + 0] * rinv;
            float v1 = acc[nt][rg * 4 + 1] * rinv;
            float v2 = acc[nt][rg * 4 + 2] * rinv;
            float v3 = acc[nt][rg * 4 + 3] * rinv;
            unsigned u = (unsigned)__builtin_amdgcn_cvt_pk_fp8_f32(v0, v1, 0, false);
            u = (unsigned)__builtin_amdgcn_cvt_pk_fp8_f32(v2, v3, u, true);
            *(unsigned*)(Opart + ((size_t)sp * T + q) * D + nt * 32 + rg * 8 + 4 * h) = u;
        }
}

// ---------------------------------------------------------------------------
// tail: blocks [0,512) = merge 16 fp8 split partials -> U_A (fp32);
//       blocks [512,576) = combine: linv from (m,l), h += ctx^T linv (atomic).
// grid 576, block 256
// ---------------------------------------------------------------------------
__global__ void tail_kernel(const unsigned char* __restrict__ Opart, const float* __restrict__ mpart,
                            const float* __restrict__ lpart, const float* __restrict__ x,
                            float* __restrict__ U_A, float* __restrict__ h) {
    __shared__ float linv_s[128];
    int t = threadIdx.x;
    if (blockIdx.x >= 512) {
        // ---- combine part ----
        int b = blockIdx.x - 512;
        if (t < 128) {
            int i = b * 128 + t;
            float mp[NSPLIT];
            float mstar = -INFINITY;
            for (int sp2 = 0; sp2 < NSPLIT; ++sp2) {
                mp[sp2] = mpart[(size_t)sp2 * T + i];
                mstar = fmaxf(mstar, mp[sp2]);
            }
            float L = 0.f;
            for (int sp2 = 0; sp2 < NSPLIT; ++sp2)
                L += __builtin_amdgcn_exp2f(mp[sp2] - mstar) * lpart[(size_t)sp2 * T + i];
            linv_s[t] = 1.0f / L;
        }
        __syncthreads();
        int d = t & 127, g = t >> 7;
        int r0 = g * 64;
        float s = 0.f;
        for (int r = 0; r < 64; ++r)
            s += x[(size_t)(b * 128 + r0 + r) * D + d] * linv_s[r0 + r];
        atomicAdd(&h[d], s);
        return;
    }
    // ---- merge part ----
    int i = blockIdx.x * 16 + (t >> 4);
    int c = t & 15;
    float mp[NSPLIT];
    float mstar = -INFINITY;
    for (int sp = 0; sp < NSPLIT; ++sp) {
        mp[sp] = mpart[(size_t)sp * T + i];
        mstar = fmaxf(mstar, mp[sp]);
    }
    float L = 0.f;
    float u[8];
    for (int k = 0; k < 8; ++k) u[k] = 0.f;
    int d0 = c * 8;
    for (int sp = 0; sp < NSPLIT; ++sp) {
        float w = __builtin_amdgcn_exp2f(mp[sp] - mstar) * lpart[(size_t)sp * T + i];
        L += w;
        uint2 ow = *(const uint2*)(Opart + ((size_t)sp * T + i) * D + d0);
        u[0] += __builtin_amdgcn_cvt_f32_fp8(ow.x, 0) * w;
        u[1] += __builtin_amdgcn_cvt_f32_fp8(ow.x, 1) * w;
        u[2] += __builtin_amdgcn_cvt_f32_fp8(ow.x, 2) * w;
        u[3] += __builtin_amdgcn_cvt_f32_fp8(ow.x, 3) * w;
        u[4] += __builtin_amdgcn_cvt_f32_fp8(ow.y, 0) * w;
        u[5] += __builtin_amdgcn_cvt_f32_fp8(ow.y, 1) * w;
        u[6] += __builtin_amdgcn_cvt_f32_fp8(ow.y, 2) * w;
        u[7] += __builtin_amdgcn_cvt_f32_fp8(ow.y, 3) * w;
    }
    float invL = 1.0f / L;
    float4 s0 = make_float4(u[0] * invL, u[1] * invL, u[2] * invL, u[3] * invL);
    float4 s1 = make_float4(u[4] * invL, u[5] * invL, u[6] * invL, u[7] * invL);
    *(float4*)(U_A + (size_t)i * D + d0) = s0;
    *(float4*)(U_A + (size_t)i * D + d0 + 4) = s1;
}

// ---------------------------------------------------------------------------
// assemble G = [ctx, U_A, ctx*U_A, ctx*h]   grid 4096, block 256, float4/thread
// ---------------------------------------------------------------------------
__global__ void assemble_kernel(const float* __restrict__ x, const float* __restrict__ U_A,
                                const float* __restrict__ h, float* __restrict__ out) {
    const float* context = x;
    int gid = blockIdx.x * 256 + threadIdx.x;
    int base = gid * 4;
    int i = base >> 9;
    int c = base & 511;
    int seg = c >> 7, d = c & 127;
    float4 r;
    if (seg == 0) {
        r = *(const float4*)(context + (size_t)i * D + d);
    } else if (seg == 1) {
        r = *(const float4*)(U_A + (size_t)i * D + d);
    } else if (seg == 2) {
        float4 a = *(const float4*)(context + (size_t)i * D + d);
        float4 b = *(const float4*)(U_A + (size_t)i * D + d);
        r = make_float4(a.x * b.x, a.y * b.y, a.z * b.z, a.w * b.w);
    } else {
        float4 a = *(const float4*)(context + (size_t)i * D + d);
        float4 b = *(const float4*)(h + d);
        r = make_float4(a.x * b.x, a.y * b.y, a.z * b.z, a.w * b.w);
    }
    *(float4*)(out + base) = r;
}

// ---------------------------------------------------------------------------
extern "C" void kernel_launch(void* const* d_in, const int* in_sizes, int n_in,
                              void* d_out, int out_size, void* d_ws, size_t ws_size,
                              hipStream_t stream) {
    const float* x = (const float*)d_in[0];
    const float* kern = (const float*)d_in[1];
    float* out = (float*)d_out;

    char* w = (char*)d_ws;
    size_t off = 0;
    _Float16* q16  = (_Float16*)(w + off); off += (size_t)T * D * 2;   // 2 MB
    _Float16* qT16 = (_Float16*)(w + off); off += (size_t)T * D * 2;   // 2 MB
    _Float16* cm16 = (_Float16*)(w + off); off += (size_t)T * D * 2;   // 2 MB
    float* qq2   = (float*)(w + off); off += (size_t)T * 4;            // 32 KB
    float* mpart = (float*)(w + off); off += (size_t)NSPLIT * T * 4;   // 512 KB
    float* lpart = (float*)(w + off); off += (size_t)NSPLIT * T * 4;   // 512 KB
    float* U_A   = (float*)(w + off); off += (size_t)T * D * 4;        // 4 MB
    float* h     = (float*)(w + off); off += (size_t)D * 4;

    // d_out doubles as fp8 split-partial scratch: 16 * T * D * 1B = 16 MB <= out
    unsigned char* Opart = (unsigned char*)d_out;

    prep_kernel<<<256, 256, 0, stream>>>(x, kern, q16, qT16, cm16, qq2, h);
    flash_kernel<<<1024, 256, 0, stream>>>(q16, qT16, cm16, qq2, Opart, mpart, lpart);
    tail_kernel<<<576, 256, 0, stream>>>(Opart, mpart, lpart, x, U_A, h);
    assemble_kernel<<<4096, 256, 0, stream>>>(x, U_A, h, out);
}

// Round 5
// 151.622 us; speedup vs baseline: 1.2181x; 1.2181x over previous
//
#include <hip/hip_runtime.h>
#include <hip/hip_bf16.h>

#define T 8192
#define D 128
#define NSPLIT 16
#define JLEN (T / NSPLIT)   /* 512 */
#define BN 64
#define NITER (JLEN / BN)   /* 8 */
#define BM 128              /* rows per workgroup */
#define LOG2E 1.44269504088896f

typedef _Float16 half2_t __attribute__((ext_vector_type(2)));
typedef _Float16 half4_t __attribute__((ext_vector_type(4)));
typedef _Float16 half8_t __attribute__((ext_vector_type(8)));
typedef __fp16 fp16x2_t __attribute__((ext_vector_type(2)));
typedef float floatx4 __attribute__((ext_vector_type(4)));
typedef float floatx16 __attribute__((ext_vector_type(16)));

typedef const __attribute__((address_space(1))) void* gas_t;
typedef __attribute__((address_space(3))) void* las_t;
__device__ __forceinline__ void gload16(const void* g, void* l) {
    __builtin_amdgcn_global_load_lds((gas_t)g, (las_t)l, 16, 0, 0);
}

// ---------------------------------------------------------------------------
// prep: q16 = f16(question), qT16 = transpose, cm16 = f16(ctx*w_m*log2e),
// qq2[j] = (question[j].w_q)*log2e.  Also zeroes h (atomic target for tail).
// grid 256 (32 rows/block), block 256
// ---------------------------------------------------------------------------
__global__ void prep_kernel(const float* __restrict__ x, const float* __restrict__ kern,
                            _Float16* __restrict__ q16, _Float16* __restrict__ qT16,
                            _Float16* __restrict__ cm16, float* __restrict__ qq2,
                            float* __restrict__ h) {
    const float* context  = x;
    const float* question = x + (size_t)T * D;
    const float* wq = kern + D;
    const float* wm = kern + 2 * D;
    __shared__ __align__(16) _Float16 tile[32][136];
    int j0 = blockIdx.x * 32;
    int t = threadIdx.x;
    if (blockIdx.x == 0 && t < 128) h[t] = 0.f;   // zero atomic accumulator
    int c4 = t & 31;       // float4 index within row (0..31)
    int rsub = t >> 5;     // 0..7
    float4 wqv = ((const float4*)wq)[c4];
    float4 wmv = ((const float4*)wm)[c4];
    for (int p = 0; p < 4; ++p) {
        int row = p * 8 + rsub;
        float4 q = ((const float4*)(question + (size_t)(j0 + row) * D))[c4];
        float4 c = ((const float4*)(context  + (size_t)(j0 + row) * D))[c4];
        half4_t qh;
        qh[0] = (_Float16)q.x; qh[1] = (_Float16)q.y; qh[2] = (_Float16)q.z; qh[3] = (_Float16)q.w;
        *(half4_t*)(q16 + (size_t)(j0 + row) * D + c4 * 4) = qh;
        *(half4_t*)&tile[row][c4 * 4] = qh;
        half4_t ch;
        ch[0] = (_Float16)(c.x * wmv.x * LOG2E); ch[1] = (_Float16)(c.y * wmv.y * LOG2E);
        ch[2] = (_Float16)(c.z * wmv.z * LOG2E); ch[3] = (_Float16)(c.w * wmv.w * LOG2E);
        *(half4_t*)(cm16 + (size_t)(j0 + row) * D + c4 * 4) = ch;
        float s = q.x * wqv.x + q.y * wqv.y + q.z * wqv.z + q.w * wqv.w;
        for (int dx = 1; dx <= 16; dx <<= 1) s += __shfl_xor(s, dx);
        if (c4 == 0) qq2[j0 + row] = s * LOG2E;
    }
    __syncthreads();
    for (int p = 0; p < 2; ++p) {
        int chunk = t + p * 256;
        int d = chunk >> 2, jo = (chunk & 3) * 8;
        half8_t v;
        for (int s2 = 0; s2 < 8; ++s2) v[s2] = tile[jo + s2][d];
        *(half8_t*)(qT16 + (size_t)d * T + j0 + jo) = v;
    }
}

// ---------------------------------------------------------------------------
// flash, 32x32x16, zero-staging-register occupancy build:
//  - R2 structure (proven 57.4us) but staging via global_load_lds width=16
//    (m97 lever): LDS dest is LINEAR, per-lane GLOBAL source carries the
//    inverse swizzle (m173).  Frees all staging VGPRs -> fits 170-reg cap.
//  - Kt[64][128] UNPADDED single-buffer, 32B-granule rotation (gg+key)&7:
//    St reads 8 lanes/bank 8 rows = b128 floor (conflict-free).
//  - Vt[2][128][64] double-buffer, 16B-granule rotation (g+dr)&7: read side
//    byte-identical to R2.
//  - bias read from global qq2 (L2-hot) -> no qqs LDS.
//  - LDS 48KB -> 3 blocks/CU; __launch_bounds__(256,3) (state ~165 <= 170).
//  - 2 barriers/iter x NITER=8 == R2's 1 x 16 total.  Fills issued a phase
//    early; barrier vmcnt-drain lands them (L2-resident K/V, ~300cy).
// grid 1024 = 64 row-blocks x 16 j-splits, block 256 (4 waves, 32 rows/wave)
// Spill tripwire: WRITE_SIZE ~17.5MB expected (Opart 16MB); >>19MB = spills.
// ---------------------------------------------------------------------------
__global__ __launch_bounds__(256, 3)
void flash_kernel(const _Float16* __restrict__ q16, const _Float16* __restrict__ qT16,
                  const _Float16* __restrict__ cm16, const float* __restrict__ qq2,
                  unsigned char* __restrict__ Opart, float* __restrict__ mpart,
                  float* __restrict__ lpart) {
    __shared__ __align__(16) _Float16 Kt[64 * 128];       // 16KB, single buffer
    __shared__ __align__(16) _Float16 Vt[2][128 * 64];    // 32KB, double buffer

    const int bx = blockIdx.x;
    const int rb = bx >> 4;
    const int sp = bx & 15;
    const int tid = threadIdx.x;
    const int wave = tid >> 6;
    const int lane = tid & 63;
    const int l31 = lane & 31;
    const int h = lane >> 5;
    const int rbase = rb * BM + wave * 32;
    const int q = rbase + l31;                  // this lane's query row
    // sigma: swap bits 2<->3 (involution). Makes St C-regs == PV B-frags.
    const int sig = (l31 & 19) | ((l31 & 4) << 1) | ((l31 & 8) >> 1);

    // ---- per-lane source offsets for the DMA fills (halves units) ----
    // K fill f (0..15): lds slot16 s = f*64 + lane -> key = f*4 + (lane>>4),
    //   phys g16 = lane&15 (ggp = g16>>1, half = g16&1);
    //   logical gg = (ggp - key)&7 -> src = q16[(jT+key)*128 + gg*16 + half*8]
    // V fill f: dr = f*8 + (lane>>3), g16p = lane&7;
    //   logical g = (g16p - dr)&7 -> src = qT16[dr*T + jT + g*8]
    int koff[4], voff[4];
#pragma unroll
    for (int k = 0; k < 4; ++k) {
        int f = wave * 4 + k;
        int key = f * 4 + (lane >> 4);
        int ggp = (lane >> 1) & 7;
        int gg = (ggp - key) & 7;
        koff[k] = key * 128 + gg * 16 + (lane & 1) * 8;
        int dr = f * 8 + (lane >> 3);
        int g = ((lane & 7) - dr) & 7;
        voff[k] = dr * T + g * 8;
    }
    _Float16* KtW = &Kt[wave * 4 * 512];                  // 4 fills * 512 halves

    // B-operand of St: lane holds cm16[q][ks*16 + h*8 + 0..7]
    half8_t qfrag[8];
#pragma unroll
    for (int ks = 0; ks < 8; ++ks)
        qfrag[ks] = *(const half8_t*)(cm16 + (size_t)q * D + ks * 16 + h * 8);

    floatx16 acc[4];   // acc[nt]: O^T tile, row = d-within-tile, col = query
#pragma unroll
    for (int nt = 0; nt < 4; ++nt)
#pragma unroll
        for (int r = 0; r < 16; ++r) acc[nt][r] = 0.f;
    float m_run = -INFINITY, l_run = 0.f;

    const int j0 = sp * JLEN;
    // ---- prologue: DMA-fill K(0) and V(0) ----
#pragma unroll
    for (int k = 0; k < 4; ++k) {
        gload16(q16 + (size_t)j0 * 128 + koff[k], KtW + k * 512);
        gload16(qT16 + (size_t)j0 + voff[k], &Vt[0][wave * 4 * 512 + k * 512]);
    }
    __syncthreads();

    for (int it = 0; it < NITER; ++it) {
        const int cur = it & 1;
        const int jT = j0 + (it + 1) * BN;
        // ---- issue V(it+1) -> Vt[cur^1] (free since before last barrier) ----
        if (it + 1 < NITER) {
#pragma unroll
            for (int k = 0; k < 4; ++k)
                gload16(qT16 + (size_t)jT + voff[k], &Vt[cur ^ 1][wave * 4 * 512 + k * 512]);
        }

        // ---- St = K Qm^T + bias (C-init from global qq2, L2-hot) ----
        // key(reg r) = (r&3) + 4*((r>>2)&1) + 8h + 16*(r>>3), key row = jt*32+sig
        floatx16 St[2];
#pragma unroll
        for (int jt = 0; jt < 2; ++jt) {
            const float4* bb = (const float4*)(qq2 + (size_t)sp * JLEN + it * 64 + jt * 32 + 8 * h);
            float4 b0 = bb[0];
            float4 b1 = bb[1];
            float4 b2 = bb[4];
            float4 b3 = bb[5];
            St[jt][0]  = b0.x; St[jt][1]  = b0.y; St[jt][2]  = b0.z; St[jt][3]  = b0.w;
            St[jt][4]  = b1.x; St[jt][5]  = b1.y; St[jt][6]  = b1.z; St[jt][7]  = b1.w;
            St[jt][8]  = b2.x; St[jt][9]  = b2.y; St[jt][10] = b2.z; St[jt][11] = b2.w;
            St[jt][12] = b3.x; St[jt][13] = b3.y; St[jt][14] = b3.z; St[jt][15] = b3.w;
        }
        __builtin_amdgcn_s_setprio(1);
#pragma unroll
        for (int ks = 0; ks < 8; ++ks) {
            int rot = ((ks + sig) & 7) << 4;
#pragma unroll
            for (int jt = 0; jt < 2; ++jt) {
                half8_t a = *(const half8_t*)&Kt[(jt * 32 + sig) * 128 + rot + h * 8];
                St[jt] = __builtin_amdgcn_mfma_f32_32x32x16_f16(a, qfrag[ks], St[jt], 0, 0, 0);
            }
        }
        __builtin_amdgcn_s_setprio(0);
        __syncthreads();   // B: all St reads of Kt done (drains V-fill too)

        // ---- issue K(it+1) -> Kt (single buffer, next read after barrier A) ----
        if (it + 1 < NITER) {
#pragma unroll
            for (int k = 0; k < 4; ++k)
                gload16(q16 + (size_t)jT * 128 + koff[k], KtW + k * 512);
        }

        // ---- online softmax (exact defer-max); tree reductions ----
        float t8[8];
#pragma unroll
        for (int r = 0; r < 8; ++r)
            t8[r] = fmaxf(fmaxf(St[0][r], St[0][r + 8]), fmaxf(St[1][r], St[1][r + 8]));
        float mx = fmaxf(fmaxf(fmaxf(t8[0], t8[4]), fmaxf(t8[1], t8[5])),
                         fmaxf(fmaxf(t8[2], t8[6]), fmaxf(t8[3], t8[7])));
        mx = fmaxf(mx, __shfl_xor(mx, 32));
        if (__any(mx > m_run)) {
            float mnew = fmaxf(m_run, mx);
            float alpha = __builtin_amdgcn_exp2f(m_run - mnew);
#pragma unroll
            for (int nt = 0; nt < 4; ++nt)
#pragma unroll
                for (int r = 0; r < 16; ++r) acc[nt][r] *= alpha;
            l_run *= alpha;
            m_run = mnew;
        }
        int pk_[2][2][4];
        float psa[4] = {0.f, 0.f, 0.f, 0.f};
#pragma unroll
        for (int jt = 0; jt < 2; ++jt)
#pragma unroll
            for (int kb = 0; kb < 2; ++kb)
#pragma unroll
                for (int r = 0; r < 4; ++r) {
                    float p0 = __builtin_amdgcn_exp2f(St[jt][kb * 8 + 2 * r]     - m_run);
                    float p1 = __builtin_amdgcn_exp2f(St[jt][kb * 8 + 2 * r + 1] - m_run);
                    psa[r] += p0 + p1;
                    fp16x2_t pk = __builtin_amdgcn_cvt_pkrtz(p0, p1);
                    pk_[jt][kb][r] = __builtin_bit_cast(int, pk);
                }
        float ps = (psa[0] + psa[1]) + (psa[2] + psa[3]);
        ps += __shfl_xor(ps, 32);
        l_run += ps;

        // ---- O^T += V^T P from Vt[cur]; B-frag = packed St regs (sigma) ----
        __builtin_amdgcn_s_setprio(1);
#pragma unroll
        for (int jt = 0; jt < 2; ++jt)
#pragma unroll
            for (int kb = 0; kb < 2; ++kb) {
                int4 w;
                w.x = pk_[jt][kb][0]; w.y = pk_[jt][kb][1];
                w.z = pk_[jt][kb][2]; w.w = pk_[jt][kb][3];
                half8_t pb = __builtin_bit_cast(half8_t, w);
                const int pg = ((jt * 4 + kb * 2 + h) + (l31 & 7)) & 7;
#pragma unroll
                for (int nt = 0; nt < 4; ++nt) {
                    half8_t va = *(const half8_t*)&Vt[cur][(nt * 32 + l31) * 64 + pg * 8];
                    acc[nt] = __builtin_amdgcn_mfma_f32_32x32x16_f16(va, pb, acc[nt], 0, 0, 0);
                }
            }
        __builtin_amdgcn_s_setprio(0);
        __syncthreads();   // A(it+1): K(it+1)/V(it+1) landed; Vt[cur] reads done
    }

    // ---- finalize: normalized O (O/l) as fp8 e4m3, 4B packed stores; m,l ----
    if (h == 0) {
        mpart[(size_t)sp * T + q] = m_run;
        lpart[(size_t)sp * T + q] = l_run;
    }
    float rinv = 1.0f / l_run;
#pragma unroll
    for (int nt = 0; nt < 4; ++nt)
#pragma unroll
        for (int rg = 0; rg < 4; ++rg) {
            float v0 = acc[nt][rg * 4 + 0] * rinv;
            float v1 = acc[nt][rg * 4 + 1] * rinv;
            float v2 = acc[nt][rg * 4 + 2] * rinv;
            float v3 = acc[nt][rg * 4 + 3] * rinv;
            unsigned u = (unsigned)__builtin_amdgcn_cvt_pk_fp8_f32(v0, v1, 0, false);
            u = (unsigned)__builtin_amdgcn_cvt_pk_fp8_f32(v2, v3, u, true);
            *(unsigned*)(Opart + ((size_t)sp * T + q) * D + nt * 32 + rg * 8 + 4 * h) = u;
        }
}

// ---------------------------------------------------------------------------
// tail: blocks [0,512) = merge 16 fp8 split partials -> U_A (fp32);
//       blocks [512,576) = combine: linv from (m,l), h += ctx^T linv (atomic).
// grid 576, block 256
// ---------------------------------------------------------------------------
__global__ void tail_kernel(const unsigned char* __restrict__ Opart, const float* __restrict__ mpart,
                            const float* __restrict__ lpart, const float* __restrict__ x,
                            float* __restrict__ U_A, float* __restrict__ h) {
    __shared__ float linv_s[128];
    int t = threadIdx.x;
    if (blockIdx.x >= 512) {
        // ---- combine part ----
        int b = blockIdx.x - 512;
        if (t < 128) {
            int i = b * 128 + t;
            float mp[NSPLIT];
            float mstar = -INFINITY;
            for (int sp2 = 0; sp2 < NSPLIT; ++sp2) {
                mp[sp2] = mpart[(size_t)sp2 * T + i];
                mstar = fmaxf(mstar, mp[sp2]);
            }
            float L = 0.f;
            for (int sp2 = 0; sp2 < NSPLIT; ++sp2)
                L += __builtin_amdgcn_exp2f(mp[sp2] - mstar) * lpart[(size_t)sp2 * T + i];
            linv_s[t] = 1.0f / L;
        }
        __syncthreads();
        int d = t & 127, g = t >> 7;
        int r0 = g * 64;
        float s = 0.f;
        for (int r = 0; r < 64; ++r)
            s += x[(size_t)(b * 128 + r0 + r) * D + d] * linv_s[r0 + r];
        atomicAdd(&h[d], s);
        return;
    }
    // ---- merge part ----
    int i = blockIdx.x * 16 + (t >> 4);
    int c = t & 15;
    float mp[NSPLIT];
    float mstar = -INFINITY;
    for (int sp = 0; sp < NSPLIT; ++sp) {
        mp[sp] = mpart[(size_t)sp * T + i];
        mstar = fmaxf(mstar, mp[sp]);
    }
    float L = 0.f;
    float u[8];
    for (int k = 0; k < 8; ++k) u[k] = 0.f;
    int d0 = c * 8;
    for (int sp = 0; sp < NSPLIT; ++sp) {
        float w = __builtin_amdgcn_exp2f(mp[sp] - mstar) * lpart[(size_t)sp * T + i];
        L += w;
        uint2 ow = *(const uint2*)(Opart + ((size_t)sp * T + i) * D + d0);
        u[0] += __builtin_amdgcn_cvt_f32_fp8(ow.x, 0) * w;
        u[1] += __builtin_amdgcn_cvt_f32_fp8(ow.x, 1) * w;
        u[2] += __builtin_amdgcn_cvt_f32_fp8(ow.x, 2) * w;
        u[3] += __builtin_amdgcn_cvt_f32_fp8(ow.x, 3) * w;
        u[4] += __builtin_amdgcn_cvt_f32_fp8(ow.y, 0) * w;
        u[5] += __builtin_amdgcn_cvt_f32_fp8(ow.y, 1) * w;
        u[6] += __builtin_amdgcn_cvt_f32_fp8(ow.y, 2) * w;
        u[7] += __builtin_amdgcn_cvt_f32_fp8(ow.y, 3) * w;
    }
    float invL = 1.0f / L;
    float4 s0 = make_float4(u[0] * invL, u[1] * invL, u[2] * invL, u[3] * invL);
    float4 s1 = make_float4(u[4] * invL, u[5] * invL, u[6] * invL, u[7] * invL);
    *(float4*)(U_A + (size_t)i * D + d0) = s0;
    *(float4*)(U_A + (size_t)i * D + d0 + 4) = s1;
}

// ---------------------------------------------------------------------------
// assemble G = [ctx, U_A, ctx*U_A, ctx*h]   grid 4096, block 256, float4/thread
// ---------------------------------------------------------------------------
__global__ void assemble_kernel(const float* __restrict__ x, const float* __restrict__ U_A,
                                const float* __restrict__ h, float* __restrict__ out) {
    const float* context = x;
    int gid = blockIdx.x * 256 + threadIdx.x;
    int base = gid * 4;
    int i = base >> 9;
    int c = base & 511;
    int seg = c >> 7, d = c & 127;
    float4 r;
    if (seg == 0) {
        r = *(const float4*)(context + (size_t)i * D + d);
    } else if (seg == 1) {
        r = *(const float4*)(U_A + (size_t)i * D + d);
    } else if (seg == 2) {
        float4 a = *(const float4*)(context + (size_t)i * D + d);
        float4 b = *(const float4*)(U_A + (size_t)i * D + d);
        r = make_float4(a.x * b.x, a.y * b.y, a.z * b.z, a.w * b.w);
    } else {
        float4 a = *(const float4*)(context + (size_t)i * D + d);
        float4 b = *(const float4*)(h + d);
        r = make_float4(a.x * b.x, a.y * b.y, a.z * b.z, a.w * b.w);
    }
    *(float4*)(out + base) = r;
}

// ---------------------------------------------------------------------------
extern "C" void kernel_launch(void* const* d_in, const int* in_sizes, int n_in,
                              void* d_out, int out_size, void* d_ws, size_t ws_size,
                              hipStream_t stream) {
    const float* x = (const float*)d_in[0];
    const float* kern = (const float*)d_in[1];
    float* out = (float*)d_out;

    char* w = (char*)d_ws;
    size_t off = 0;
    _Float16* q16  = (_Float16*)(w + off); off += (size_t)T * D * 2;   // 2 MB
    _Float16* qT16 = (_Float16*)(w + off); off += (size_t)T * D * 2;   // 2 MB
    _Float16* cm16 = (_Float16*)(w + off); off += (size_t)T * D * 2;   // 2 MB
    float* qq2   = (float*)(w + off); off += (size_t)T * 4;            // 32 KB
    float* mpart = (float*)(w + off); off += (size_t)NSPLIT * T * 4;   // 512 KB
    float* lpart = (float*)(w + off); off += (size_t)NSPLIT * T * 4;   // 512 KB
    float* U_A   = (float*)(w + off); off += (size_t)T * D * 4;        // 4 MB
    float* h     = (float*)(w + off); off += (size_t)D * 4;

    // d_out doubles as fp8 split-partial scratch: 16 * T * D * 1B = 16 MB = out
    unsigned char* Opart = (unsigned char*)d_out;

    prep_kernel<<<256, 256, 0, stream>>>(x, kern, q16, qT16, cm16, qq2, h);
    flash_kernel<<<1024, 256, 0, stream>>>(q16, qT16, cm16, qq2, Opart, mpart, lpart);
    tail_kernel<<<576, 256, 0, stream>>>(Opart, mpart, lpart, x, U_A, h);
    assemble_kernel<<<4096, 256, 0, stream>>>(x, U_A, h, out);
}

// Round 6
// 132.775 us; speedup vs baseline: 1.3910x; 1.1419x over previous
//
#include <hip/hip_runtime.h>
#include <hip/hip_bf16.h>

#define T 8192
#define D 128
#define NSPLIT 16
#define JLEN (T / NSPLIT)   /* 512 */
#define BN 32
#define NITER (JLEN / BN)   /* 16 */
#define BM 128              /* rows per workgroup */
#define LOG2E 1.44269504088896f

typedef _Float16 half2_t __attribute__((ext_vector_type(2)));
typedef _Float16 half4_t __attribute__((ext_vector_type(4)));
typedef _Float16 half8_t __attribute__((ext_vector_type(8)));
typedef __fp16 fp16x2_t __attribute__((ext_vector_type(2)));
typedef float floatx4 __attribute__((ext_vector_type(4)));
typedef float floatx16 __attribute__((ext_vector_type(16)));

// ---------------------------------------------------------------------------
// prep: q16 = f16(question), qT16 = transpose, cm16 = f16(ctx*w_m*log2e),
// qq2[j] = (question[j].w_q)*log2e.  Also zeroes h (atomic target for tail).
// grid 256 (32 rows/block), block 256
// ---------------------------------------------------------------------------
__global__ void prep_kernel(const float* __restrict__ x, const float* __restrict__ kern,
                            _Float16* __restrict__ q16, _Float16* __restrict__ qT16,
                            _Float16* __restrict__ cm16, float* __restrict__ qq2,
                            float* __restrict__ h) {
    const float* context  = x;
    const float* question = x + (size_t)T * D;
    const float* wq = kern + D;
    const float* wm = kern + 2 * D;
    __shared__ __align__(16) _Float16 tile[32][136];
    int j0 = blockIdx.x * 32;
    int t = threadIdx.x;
    if (blockIdx.x == 0 && t < 128) h[t] = 0.f;   // zero atomic accumulator
    int c4 = t & 31;       // float4 index within row (0..31)
    int rsub = t >> 5;     // 0..7
    float4 wqv = ((const float4*)wq)[c4];
    float4 wmv = ((const float4*)wm)[c4];
    for (int p = 0; p < 4; ++p) {
        int row = p * 8 + rsub;
        float4 q = ((const float4*)(question + (size_t)(j0 + row) * D))[c4];
        float4 c = ((const float4*)(context  + (size_t)(j0 + row) * D))[c4];
        half4_t qh;
        qh[0] = (_Float16)q.x; qh[1] = (_Float16)q.y; qh[2] = (_Float16)q.z; qh[3] = (_Float16)q.w;
        *(half4_t*)(q16 + (size_t)(j0 + row) * D + c4 * 4) = qh;
        *(half4_t*)&tile[row][c4 * 4] = qh;
        half4_t ch;
        ch[0] = (_Float16)(c.x * wmv.x * LOG2E); ch[1] = (_Float16)(c.y * wmv.y * LOG2E);
        ch[2] = (_Float16)(c.z * wmv.z * LOG2E); ch[3] = (_Float16)(c.w * wmv.w * LOG2E);
        *(half4_t*)(cm16 + (size_t)(j0 + row) * D + c4 * 4) = ch;
        float s = q.x * wqv.x + q.y * wqv.y + q.z * wqv.z + q.w * wqv.w;
        for (int dx = 1; dx <= 16; dx <<= 1) s += __shfl_xor(s, dx);
        if (c4 == 0) qq2[j0 + row] = s * LOG2E;
    }
    __syncthreads();
    for (int p = 0; p < 2; ++p) {
        int chunk = t + p * 256;
        int d = chunk >> 2, jo = (chunk & 3) * 8;
        half8_t v;
        for (int s2 = 0; s2 < 8; ++s2) v[s2] = tile[jo + s2][d];
        *(half8_t*)(qT16 + (size_t)d * T + j0 + jo) = v;
    }
}

// ---------------------------------------------------------------------------
// flash, 32x32x16, 3-blocks/CU reg-staged build (R2 pipeline + R5 reg budget):
//  - R2's proven structure (reg staging w/ full-iteration prefetch depth,
//    sigma bits2<->3 trick so St C-regs == PV B-frags, stride-136 Kt,
//    rotated Vt, exact defer-max, fp8 finalize) at HALF tile (BN=32):
//    St 16 regs, staging 16 regs -> ~160 total <= 168 cap of 3 waves/SIMD.
//  - LDS 26.7KB: Kt single [32][136] 8.7K + Vt[2][128][32] 16K + qqs 2K.
//  - single-K-buffer => 2 barriers/iter: St reads Kt -> barrier B ->
//    commit K(it+1) -> softmax+PV -> barrier A.  V double-buffered: commit
//    V(it+1) at iter top (buffer last read in PV(it-1), fenced by barrier A).
//  - global reloads issued immediately after each commit -> ~1 iter of
//    latency slack (R2-proven; R5's DMA fills lost this to vmcnt(0) drains).
// grid 1024 = 64 row-blocks x 16 j-splits, block 256 (4 waves, 32 rows/wave)
// 768 resident + 256 staggered tail (4/3 rounds).
// Spill tripwire: WRITE_SIZE ~17.5MB clean; >>34MB = spills = abandon.
// ---------------------------------------------------------------------------
__global__ __launch_bounds__(256, 3)
void flash_kernel(const _Float16* __restrict__ q16, const _Float16* __restrict__ qT16,
                  const _Float16* __restrict__ cm16, const float* __restrict__ qq2,
                  unsigned char* __restrict__ Opart, float* __restrict__ mpart,
                  float* __restrict__ lpart) {
    __shared__ __align__(16) _Float16 Kt[32][136];     // [key][d], stride 272B, single buf
    __shared__ __align__(16) _Float16 Vt[2][128][32];  // [d][rotated key granule]
    __shared__ __align__(16) float qqs[JLEN];          // biases for this split (2KB)

    const int bx = blockIdx.x;
    const int rb = bx >> 4;
    const int sp = bx & 15;
    const int tid = threadIdx.x;
    const int wave = tid >> 6;
    const int lane = tid & 63;
    const int l31 = lane & 31;
    const int h = lane >> 5;
    const int rbase = rb * BM + wave * 32;
    const int q = rbase + l31;                  // this lane's query row
    // sigma: swap bits 2<->3 (involution). Makes St C-regs == PV B-frags.
    const int sig = (l31 & 19) | ((l31 & 4) << 1) | ((l31 & 8) >> 1);

    if (tid < 128) ((float4*)qqs)[tid] = ((const float4*)(qq2 + (size_t)sp * JLEN))[tid];

    // B-operand of St: lane holds cm16[q][ks*16 + h*8 + 0..7]
    half8_t qfrag[8];
#pragma unroll
    for (int ks = 0; ks < 8; ++ks)
        qfrag[ks] = *(const half8_t*)(cm16 + (size_t)q * D + ks * 16 + h * 8);

    floatx16 acc[4];   // acc[nt]: O^T tile, row = d-within-tile, col = query
#pragma unroll
    for (int nt = 0; nt < 4; ++nt)
#pragma unroll
        for (int r = 0; r < 16; ++r) acc[nt][r] = 0.f;
    float m_run = -INFINITY, l_run = 0.f;

    const int j0 = sp * JLEN;
    half8_t kreg[2], vreg[2];
    // ---- prologue: tile 0 -> LDS, tile 1 -> regs ----
#pragma unroll
    for (int k = 0; k < 2; ++k) {
        int idx = tid + k * 256;
        kreg[k] = *(const half8_t*)(q16 + (size_t)(j0 + (idx >> 4)) * D + (idx & 15) * 8);
        vreg[k] = *(const half8_t*)(qT16 + (size_t)(idx >> 2) * T + j0 + (idx & 3) * 8);
    }
#pragma unroll
    for (int k = 0; k < 2; ++k) {
        int idx = tid + k * 256;
        *(half8_t*)&Kt[idx >> 4][(idx & 15) * 8] = kreg[k];
        int dr = idx >> 2, c4g = idx & 3;
        *(half8_t*)&Vt[0][dr][((c4g + dr) & 3) * 8] = vreg[k];
    }
#pragma unroll
    for (int k = 0; k < 2; ++k) {
        int idx = tid + k * 256;
        kreg[k] = *(const half8_t*)(q16 + (size_t)(j0 + BN + (idx >> 4)) * D + (idx & 15) * 8);
        vreg[k] = *(const half8_t*)(qT16 + (size_t)(idx >> 2) * T + j0 + BN + (idx & 3) * 8);
    }
    __syncthreads();

    for (int it = 0; it < NITER; ++it) {
        const int cur = it & 1;
        // ---- commit V(it+1) -> Vt[cur^1] (fenced from PV(it-1) by barrier A) ----
        if (it + 1 < NITER) {
#pragma unroll
            for (int k = 0; k < 2; ++k) {
                int idx = tid + k * 256;
                int dr = idx >> 2, c4g = idx & 3;
                *(half8_t*)&Vt[cur ^ 1][dr][((c4g + dr) & 3) * 8] = vreg[k];
            }
        }
        // ---- reload vreg <- V(it+2): ~1 iteration of latency slack ----
        if (it + 2 < NITER) {
            int jn = j0 + (it + 2) * BN;
#pragma unroll
            for (int k = 0; k < 2; ++k) {
                int idx = tid + k * 256;
                vreg[k] = *(const half8_t*)(qT16 + (size_t)(idx >> 2) * T + jn + (idx & 3) * 8);
            }
        }

        // ---- St = K Qm^T + bias (C-init); key(reg r) =
        //      (r&3) + 4*((r>>2)&1) + 8h + 16*(r>>3)
        floatx16 St;
        {
            const float* qb = &qqs[it * 32];
            float4 b0 = *(const float4*)(qb + 8 * h);
            float4 b1 = *(const float4*)(qb + 4 + 8 * h);
            float4 b2 = *(const float4*)(qb + 16 + 8 * h);
            float4 b3 = *(const float4*)(qb + 20 + 8 * h);
            St[0]  = b0.x; St[1]  = b0.y; St[2]  = b0.z; St[3]  = b0.w;
            St[4]  = b1.x; St[5]  = b1.y; St[6]  = b1.z; St[7]  = b1.w;
            St[8]  = b2.x; St[9]  = b2.y; St[10] = b2.z; St[11] = b2.w;
            St[12] = b3.x; St[13] = b3.y; St[14] = b3.z; St[15] = b3.w;
            __builtin_amdgcn_s_setprio(1);
#pragma unroll
            for (int ks = 0; ks < 8; ++ks) {
                half8_t a = *(const half8_t*)&Kt[sig][ks * 16 + h * 8];
                St = __builtin_amdgcn_mfma_f32_32x32x16_f16(a, qfrag[ks], St, 0, 0, 0);
            }
            __builtin_amdgcn_s_setprio(0);
        }
        __syncthreads();   // barrier B: all waves' St reads of Kt complete

        // ---- commit K(it+1) -> Kt (single buffer); reload kreg <- K(it+2) ----
        if (it + 1 < NITER) {
#pragma unroll
            for (int k = 0; k < 2; ++k) {
                int idx = tid + k * 256;
                *(half8_t*)&Kt[idx >> 4][(idx & 15) * 8] = kreg[k];
            }
        }
        if (it + 2 < NITER) {
            int jn = j0 + (it + 2) * BN;
#pragma unroll
            for (int k = 0; k < 2; ++k) {
                int idx = tid + k * 256;
                kreg[k] = *(const half8_t*)(q16 + (size_t)(jn + (idx >> 4)) * D + (idx & 15) * 8);
            }
        }

        // ---- online softmax (exact defer-max); tree reductions ----
        float t4[4];
#pragma unroll
        for (int r = 0; r < 4; ++r)
            t4[r] = fmaxf(fmaxf(St[r], St[r + 4]), fmaxf(St[r + 8], St[r + 12]));
        float mx = fmaxf(fmaxf(t4[0], t4[1]), fmaxf(t4[2], t4[3]));
        mx = fmaxf(mx, __shfl_xor(mx, 32));
        if (__any(mx > m_run)) {
            float mnew = fmaxf(m_run, mx);
            float alpha = __builtin_amdgcn_exp2f(m_run - mnew);
#pragma unroll
            for (int nt = 0; nt < 4; ++nt)
#pragma unroll
                for (int r = 0; r < 16; ++r) acc[nt][r] *= alpha;
            l_run *= alpha;
            m_run = mnew;
        }
        int pk_[2][4];
        float psa[4] = {0.f, 0.f, 0.f, 0.f};
#pragma unroll
        for (int kb = 0; kb < 2; ++kb)
#pragma unroll
            for (int r = 0; r < 4; ++r) {
                float p0 = __builtin_amdgcn_exp2f(St[kb * 8 + 2 * r]     - m_run);
                float p1 = __builtin_amdgcn_exp2f(St[kb * 8 + 2 * r + 1] - m_run);
                psa[r] += p0 + p1;
                fp16x2_t pk = __builtin_amdgcn_cvt_pkrtz(p0, p1);
                pk_[kb][r] = __builtin_bit_cast(int, pk);
            }
        float ps = (psa[0] + psa[1]) + (psa[2] + psa[3]);
        ps += __shfl_xor(ps, 32);
        l_run += ps;

        // ---- O^T += V^T P from Vt[cur]; B-frag = packed St regs (sigma) ----
        __builtin_amdgcn_s_setprio(1);
#pragma unroll
        for (int kb = 0; kb < 2; ++kb) {
            int4 w;
            w.x = pk_[kb][0]; w.y = pk_[kb][1];
            w.z = pk_[kb][2]; w.w = pk_[kb][3];
            half8_t pb = __builtin_bit_cast(half8_t, w);
            const int pg = ((kb * 2 + h) + l31) & 3;
#pragma unroll
            for (int nt = 0; nt < 4; ++nt) {
                half8_t va = *(const half8_t*)&Vt[cur][nt * 32 + l31][pg * 8];
                acc[nt] = __builtin_amdgcn_mfma_f32_32x32x16_f16(va, pb, acc[nt], 0, 0, 0);
            }
        }
        __builtin_amdgcn_s_setprio(0);
        __syncthreads();   // barrier A: K(it+1) committed; Vt[cur] reads done
    }

    // ---- finalize: normalized O (O/l) as fp8 e4m3, 4B packed stores; m,l ----
    if (h == 0) {
        mpart[(size_t)sp * T + q] = m_run;
        lpart[(size_t)sp * T + q] = l_run;
    }
    float rinv = 1.0f / l_run;
#pragma unroll
    for (int nt = 0; nt < 4; ++nt)
#pragma unroll
        for (int rg = 0; rg < 4; ++rg) {
            float v0 = acc[nt][rg * 4 + 0] * rinv;
            float v1 = acc[nt][rg * 4 + 1] * rinv;
            float v2 = acc[nt][rg * 4 + 2] * rinv;
            float v3 = acc[nt][rg * 4 + 3] * rinv;
            unsigned u = (unsigned)__builtin_amdgcn_cvt_pk_fp8_f32(v0, v1, 0, false);
            u = (unsigned)__builtin_amdgcn_cvt_pk_fp8_f32(v2, v3, u, true);
            *(unsigned*)(Opart + ((size_t)sp * T + q) * D + nt * 32 + rg * 8 + 4 * h) = u;
        }
}

// ---------------------------------------------------------------------------
// tail: blocks [0,512) = merge 16 fp8 split partials -> U_A (fp32);
//       blocks [512,576) = combine: linv from (m,l), h += ctx^T linv (atomic).
// grid 576, block 256
// ---------------------------------------------------------------------------
__global__ void tail_kernel(const unsigned char* __restrict__ Opart, const float* __restrict__ mpart,
                            const float* __restrict__ lpart, const float* __restrict__ x,
                            float* __restrict__ U_A, float* __restrict__ h) {
    __shared__ float linv_s[128];
    int t = threadIdx.x;
    if (blockIdx.x >= 512) {
        // ---- combine part ----
        int b = blockIdx.x - 512;
        if (t < 128) {
            int i = b * 128 + t;
            float mp[NSPLIT];
            float mstar = -INFINITY;
            for (int sp2 = 0; sp2 < NSPLIT; ++sp2) {
                mp[sp2] = mpart[(size_t)sp2 * T + i];
                mstar = fmaxf(mstar, mp[sp2]);
            }
            float L = 0.f;
            for (int sp2 = 0; sp2 < NSPLIT; ++sp2)
                L += __builtin_amdgcn_exp2f(mp[sp2] - mstar) * lpart[(size_t)sp2 * T + i];
            linv_s[t] = 1.0f / L;
        }
        __syncthreads();
        int d = t & 127, g = t >> 7;
        int r0 = g * 64;
        float s = 0.f;
        for (int r = 0; r < 64; ++r)
            s += x[(size_t)(b * 128 + r0 + r) * D + d] * linv_s[r0 + r];
        atomicAdd(&h[d], s);
        return;
    }
    // ---- merge part ----
    int i = blockIdx.x * 16 + (t >> 4);
    int c = t & 15;
    float mp[NSPLIT];
    float mstar = -INFINITY;
    for (int sp = 0; sp < NSPLIT; ++sp) {
        mp[sp] = mpart[(size_t)sp * T + i];
        mstar = fmaxf(mstar, mp[sp]);
    }
    float L = 0.f;
    float u[8];
    for (int k = 0; k < 8; ++k) u[k] = 0.f;
    int d0 = c * 8;
    for (int sp = 0; sp < NSPLIT; ++sp) {
        float w = __builtin_amdgcn_exp2f(mp[sp] - mstar) * lpart[(size_t)sp * T + i];
        L += w;
        uint2 ow = *(const uint2*)(Opart + ((size_t)sp * T + i) * D + d0);
        u[0] += __builtin_amdgcn_cvt_f32_fp8(ow.x, 0) * w;
        u[1] += __builtin_amdgcn_cvt_f32_fp8(ow.x, 1) * w;
        u[2] += __builtin_amdgcn_cvt_f32_fp8(ow.x, 2) * w;
        u[3] += __builtin_amdgcn_cvt_f32_fp8(ow.x, 3) * w;
        u[4] += __builtin_amdgcn_cvt_f32_fp8(ow.y, 0) * w;
        u[5] += __builtin_amdgcn_cvt_f32_fp8(ow.y, 1) * w;
        u[6] += __builtin_amdgcn_cvt_f32_fp8(ow.y, 2) * w;
        u[7] += __builtin_amdgcn_cvt_f32_fp8(ow.y, 3) * w;
    }
    float invL = 1.0f / L;
    float4 s0 = make_float4(u[0] * invL, u[1] * invL, u[2] * invL, u[3] * invL);
    float4 s1 = make_float4(u[4] * invL, u[5] * invL, u[6] * invL, u[7] * invL);
    *(float4*)(U_A + (size_t)i * D + d0) = s0;
    *(float4*)(U_A + (size_t)i * D + d0 + 4) = s1;
}

// ---------------------------------------------------------------------------
// assemble G = [ctx, U_A, ctx*U_A, ctx*h]   grid 4096, block 256, float4/thread
// ---------------------------------------------------------------------------
__global__ void assemble_kernel(const float* __restrict__ x, const float* __restrict__ U_A,
                                const float* __restrict__ h, float* __restrict__ out) {
    const float* context = x;
    int gid = blockIdx.x * 256 + threadIdx.x;
    int base = gid * 4;
    int i = base >> 9;
    int c = base & 511;
    int seg = c >> 7, d = c & 127;
    float4 r;
    if (seg == 0) {
        r = *(const float4*)(context + (size_t)i * D + d);
    } else if (seg == 1) {
        r = *(const float4*)(U_A + (size_t)i * D + d);
    } else if (seg == 2) {
        float4 a = *(const float4*)(context + (size_t)i * D + d);
        float4 b = *(const float4*)(U_A + (size_t)i * D + d);
        r = make_float4(a.x * b.x, a.y * b.y, a.z * b.z, a.w * b.w);
    } else {
        float4 a = *(const float4*)(context + (size_t)i * D + d);
        float4 b = *(const float4*)(h + d);
        r = make_float4(a.x * b.x, a.y * b.y, a.z * b.z, a.w * b.w);
    }
    *(float4*)(out + base) = r;
}

// ---------------------------------------------------------------------------
extern "C" void kernel_launch(void* const* d_in, const int* in_sizes, int n_in,
                              void* d_out, int out_size, void* d_ws, size_t ws_size,
                              hipStream_t stream) {
    const float* x = (const float*)d_in[0];
    const float* kern = (const float*)d_in[1];
    float* out = (float*)d_out;

    char* w = (char*)d_ws;
    size_t off = 0;
    _Float16* q16  = (_Float16*)(w + off); off += (size_t)T * D * 2;   // 2 MB
    _Float16* qT16 = (_Float16*)(w + off); off += (size_t)T * D * 2;   // 2 MB
    _Float16* cm16 = (_Float16*)(w + off); off += (size_t)T * D * 2;   // 2 MB
    float* qq2   = (float*)(w + off); off += (size_t)T * 4;            // 32 KB
    float* mpart = (float*)(w + off); off += (size_t)NSPLIT * T * 4;   // 512 KB
    float* lpart = (float*)(w + off); off += (size_t)NSPLIT * T * 4;   // 512 KB
    float* U_A   = (float*)(w + off); off += (size_t)T * D * 4;        // 4 MB
    float* h     = (float*)(w + off); off += (size_t)D * 4;

    // d_out doubles as fp8 split-partial scratch: 16 * T * D * 1B = 16 MB = out
    unsigned char* Opart = (unsigned char*)d_out;

    prep_kernel<<<256, 256, 0, stream>>>(x, kern, q16, qT16, cm16, qq2, h);
    flash_kernel<<<1024, 256, 0, stream>>>(q16, qT16, cm16, qq2, Opart, mpart, lpart);
    tail_kernel<<<576, 256, 0, stream>>>(Opart, mpart, lpart, x, U_A, h);
    assemble_kernel<<<4096, 256, 0, stream>>>(x, U_A, h, out);
}